// Round 1
// baseline (132.162 us; speedup 1.0000x reference)
//
#include <hip/hip_runtime.h>

typedef unsigned short u16;
typedef __bf16 bf16x8 __attribute__((ext_vector_type(8)));
typedef float f32x4 __attribute__((ext_vector_type(4)));

#define WEMD 400
#define RANK 396
#define NA   16384     // SEQ*BATCH
#define KP   416       // padded k (396->416) and wemd (400->416)
#define HSTR 512       // H row stride in elements
#define NBC  2500
#define NBCP 2560

// ---- ws layout (bytes) ----
#define OFF_WBF  0u                 // u16 [16416][416]  = 13,658,112 B
#define OFF_UBT  13658112u          // u16 [512][416]    =    425,984 B
#define OFF_TBT  14084096u          // u16 [512][416]
#define OFF_G2   14510080u          // f32 [50][416]     =     83,200 B
#define OFF_G3   14593280u
#define OFF_G    14676480u          // u16 [2560][416]   =  2,129,920 B
#define OFF_H    16806400u          // u16 [16384][512]  = 16,777,216 B  (total ~33.6 MB)

__device__ __forceinline__ u16 f2bf(float f) {
  union { float f; unsigned u; } v; v.f = f;
  unsigned u = v.u;
  return (u16)((u + 0x7FFFu + ((u >> 16) & 1u)) >> 16);  // RNE
}

typedef __attribute__((address_space(3))) unsigned char lds_byte;
typedef __attribute__((address_space(1))) const unsigned char glob_byte;

__device__ __forceinline__ void gload16(const void* g, void* l) {
  __builtin_amdgcn_global_load_lds((glob_byte*)g, (lds_byte*)l, 16, 0, 0);
}

// ---------- prep kernels ----------
__global__ void prep_w(const float* __restrict__ word, const float* __restrict__ first,
                       u16* __restrict__ Wbf) {
  int idx = blockIdx.x * 256 + threadIdx.x;           // over 16416*416
  if (idx >= 16416 * KP) return;
  int r = idx / KP, c = idx - r * KP;
  float v = 0.f;
  if (c < WEMD) v = (r < 32) ? first[c] : word[(size_t)(r - 32) * WEMD + c];
  Wbf[idx] = f2bf(v);
}

__global__ void prep_ut(const float* __restrict__ U, const float* __restrict__ T,
                        u16* __restrict__ Ubt, u16* __restrict__ Tbt) {
  int idx = blockIdx.x * 256 + threadIdx.x;           // over 512*416
  if (idx >= 512 * KP) return;
  int n = idx / KP, k = idx - n * KP;
  float u = 0.f, t = 0.f;
  if (n < RANK && k < WEMD) { u = U[(size_t)k * RANK + n]; t = T[(size_t)k * RANK + n]; }
  Ubt[idx] = f2bf(u); Tbt[idx] = f2bf(t);
}

__global__ void prep_g23(const float* __restrict__ tag, const float* __restrict__ V,
                         const float* __restrict__ W, float* __restrict__ g2f,
                         float* __restrict__ g3f) {
  int idx = blockIdx.x * 256 + threadIdx.x;           // over 50*416
  if (idx >= 50 * KP) return;
  int b = idx / KP, k = idx - b * KP;
  float a2 = 0.f, a3 = 0.f;
  if (k < RANK) {
    #pragma unroll
    for (int e = 0; e < 20; ++e) {
      float te = tag[b * 20 + e];
      a2 += te * V[e * RANK + k];
      a3 += te * W[e * RANK + k];
    }
  }
  g2f[idx] = a2; g3f[idx] = a3;
}

__global__ void prep_G(const float* __restrict__ g2f, const float* __restrict__ g3f,
                       u16* __restrict__ G) {
  int idx = blockIdx.x * 256 + threadIdx.x;           // over 2560*416
  if (idx >= NBCP * KP) return;
  int bc = idx / KP, k = idx - bc * KP;
  float v = 0.f;
  if (bc < NBC) {
    int b = bc / 50, c = bc - b * 50;
    v = g2f[b * KP + k] * g3f[c * KP + k];            // g2f/g3f zero-padded past 396
  }
  G[idx] = f2bf(v);
}

// ---------- H = (word@U) * (neighbor@T), bf16 out ----------
// M=16384, N=512 (396 valid + zero pad), K=416.  A row stride 832B, B^T row stride 832B.
__global__ __launch_bounds__(256) void gemm_h(const u16* __restrict__ Wbf,
                                              const u16* __restrict__ Ubt,
                                              const u16* __restrict__ Tbt,
                                              u16* __restrict__ H) {
  __shared__ u16 As0[128 * 32], As1[128 * 32], Bu[128 * 32], Bt[128 * 32];
  const int tid = threadIdx.x;
  const int l = tid & 63, w = tid >> 6;
  const int wm = w >> 1, wn = w & 1;
  const int tm = (blockIdx.x >> 2) * 128, tn = (blockIdx.x & 3) * 128;

  f32x4 acc0[4][4] = {}, acc1[4][4] = {};

  const int srow = tid >> 2;            // 0..63
  const int scolb = (tid & 3) * 16;     // byte offset within 64B row-k chunk
  const char* gA0 = (const char*)Wbf + (size_t)(tm + 32 + srow) * 832 + scolb;
  const char* gA1 = (const char*)Wbf + (size_t)(tm + srow) * 832 + scolb;
  const char* gU  = (const char*)Ubt + (size_t)(tn + srow) * 832 + scolb;
  const char* gT  = (const char*)Tbt + (size_t)(tn + srow) * 832 + scolb;
  char* lA0 = (char*)As0 + tid * 16;
  char* lA1 = (char*)As1 + tid * 16;
  char* lU  = (char*)Bu  + tid * 16;
  char* lT  = (char*)Bt  + tid * 16;

  const int fo_a = (wm * 64 + (l & 15)) * 32 + (l >> 4) * 8;
  const int fo_b = (wn * 64 + (l & 15)) * 32 + (l >> 4) * 8;

  for (int kt = 0; kt < 13; ++kt) {
    const int kb = kt * 64;
    gload16(gA0 + kb, lA0); gload16(gA0 + kb + (size_t)64 * 832, lA0 + 4096);
    gload16(gA1 + kb, lA1); gload16(gA1 + kb + (size_t)64 * 832, lA1 + 4096);
    gload16(gU  + kb, lU ); gload16(gU  + kb + (size_t)64 * 832, lU  + 4096);
    gload16(gT  + kb, lT ); gload16(gT  + kb + (size_t)64 * 832, lT  + 4096);
    __syncthreads();
    bf16x8 a0[4], a1[4], bu[4], bt[4];
    #pragma unroll
    for (int i = 0; i < 4; ++i) {
      a0[i] = *(const bf16x8*)(As0 + fo_a + i * 16 * 32);
      a1[i] = *(const bf16x8*)(As1 + fo_a + i * 16 * 32);
      bu[i] = *(const bf16x8*)(Bu  + fo_b + i * 16 * 32);
      bt[i] = *(const bf16x8*)(Bt  + fo_b + i * 16 * 32);
    }
    #pragma unroll
    for (int i = 0; i < 4; ++i)
      #pragma unroll
      for (int j = 0; j < 4; ++j) {
        acc0[i][j] = __builtin_amdgcn_mfma_f32_16x16x32_bf16(a0[i], bu[j], acc0[i][j], 0, 0, 0);
        acc1[i][j] = __builtin_amdgcn_mfma_f32_16x16x32_bf16(a1[i], bt[j], acc1[i][j], 0, 0, 0);
      }
    __syncthreads();
  }

  const int r4 = (l >> 4) * 4, cc = l & 15;
  #pragma unroll
  for (int i = 0; i < 4; ++i)
    #pragma unroll
    for (int j = 0; j < 4; ++j) {
      const int col = tn + wn * 64 + j * 16 + cc;
      #pragma unroll
      for (int r = 0; r < 4; ++r) {
        const int rowg = tm + wm * 64 + i * 16 + r4 + r;
        H[(size_t)rowg * HSTR + col] = f2bf(acc0[i][j][r] * acc1[i][j][r]);
      }
    }
}

// ---------- out[16384,2500] = H[.,416] @ G^T ----------
// A row stride 1024B (HSTR=512), B^T row stride 832B, K=416, N tiles of 128 (20), M tiles 128.
__global__ __launch_bounds__(256) void gemm_big(const u16* __restrict__ H,
                                                const u16* __restrict__ G,
                                                float* __restrict__ out) {
  __shared__ u16 As[128 * 32], Bs[128 * 32];
  const int tid = threadIdx.x;
  const int l = tid & 63, w = tid >> 6;
  const int wm = w >> 1, wn = w & 1;
  const int tm = (blockIdx.x / 20) * 128, tn = (blockIdx.x % 20) * 128;

  f32x4 acc[4][4] = {};

  const int srow = tid >> 2;
  const int scolb = (tid & 3) * 16;
  const char* gA = (const char*)H + (size_t)(tm + srow) * 1024 + scolb;
  const char* gB = (const char*)G + (size_t)(tn + srow) * 832 + scolb;
  char* lA = (char*)As + tid * 16;
  char* lB = (char*)Bs + tid * 16;

  const int fo_a = (wm * 64 + (l & 15)) * 32 + (l >> 4) * 8;
  const int fo_b = (wn * 64 + (l & 15)) * 32 + (l >> 4) * 8;

  for (int kt = 0; kt < 13; ++kt) {
    const int kb = kt * 64;
    gload16(gA + kb, lA); gload16(gA + kb + (size_t)64 * 1024, lA + 4096);
    gload16(gB + kb, lB); gload16(gB + kb + (size_t)64 * 832,  lB + 4096);
    __syncthreads();
    bf16x8 a[4], b[4];
    #pragma unroll
    for (int i = 0; i < 4; ++i) {
      a[i] = *(const bf16x8*)(As + fo_a + i * 16 * 32);
      b[i] = *(const bf16x8*)(Bs + fo_b + i * 16 * 32);
    }
    #pragma unroll
    for (int i = 0; i < 4; ++i)
      #pragma unroll
      for (int j = 0; j < 4; ++j)
        acc[i][j] = __builtin_amdgcn_mfma_f32_16x16x32_bf16(a[i], b[j], acc[i][j], 0, 0, 0);
    __syncthreads();
  }

  const int r4 = (l >> 4) * 4, cc = l & 15;
  #pragma unroll
  for (int i = 0; i < 4; ++i)
    #pragma unroll
    for (int j = 0; j < 4; ++j) {
      const int col = tn + wn * 64 + j * 16 + cc;
      if (col < NBC) {
        #pragma unroll
        for (int r = 0; r < 4; ++r) {
          const int rowg = tm + wm * 64 + i * 16 + r4 + r;
          out[(size_t)rowg * NBC + col] = acc[i][j][r];
        }
      }
    }
}

extern "C" void kernel_launch(void* const* d_in, const int* in_sizes, int n_in,
                              void* d_out, int out_size, void* d_ws, size_t ws_size,
                              hipStream_t stream) {
  const float* word  = (const float*)d_in[0];
  const float* tag   = (const float*)d_in[1];
  const float* Tm    = (const float*)d_in[2];
  const float* Um    = (const float*)d_in[3];
  const float* Vm    = (const float*)d_in[4];
  const float* Wm    = (const float*)d_in[5];
  const float* first = (const float*)d_in[6];
  float* out = (float*)d_out;
  char* ws = (char*)d_ws;

  u16*   Wbf = (u16*)(ws + OFF_WBF);
  u16*   Ubt = (u16*)(ws + OFF_UBT);
  u16*   Tbt = (u16*)(ws + OFF_TBT);
  float* g2f = (float*)(ws + OFF_G2);
  float* g3f = (float*)(ws + OFF_G3);
  u16*   G   = (u16*)(ws + OFF_G);
  u16*   H   = (u16*)(ws + OFF_H);

  hipLaunchKernelGGL(prep_w,   dim3((16416 * KP + 255) / 256), dim3(256), 0, stream, word, first, Wbf);
  hipLaunchKernelGGL(prep_ut,  dim3((512 * KP + 255) / 256),   dim3(256), 0, stream, Um, Tm, Ubt, Tbt);
  hipLaunchKernelGGL(prep_g23, dim3((50 * KP + 255) / 256),    dim3(256), 0, stream, tag, Vm, Wm, g2f, g3f);
  hipLaunchKernelGGL(prep_G,   dim3((NBCP * KP + 255) / 256),  dim3(256), 0, stream, g2f, g3f, G);
  hipLaunchKernelGGL(gemm_h,   dim3(128 * 4),  dim3(256), 0, stream, Wbf, Ubt, Tbt, H);
  hipLaunchKernelGGL(gemm_big, dim3(128 * 20), dim3(256), 0, stream, H, G, out);
}

// Round 2
// 126.909 us; speedup vs baseline: 1.0414x; 1.0414x over previous
//
#include <hip/hip_runtime.h>

typedef unsigned short u16;
typedef __bf16 bf16x8 __attribute__((ext_vector_type(8)));
typedef float f32x4 __attribute__((ext_vector_type(4)));

#define WEMD 400
#define RANK 396
#define NA   16384     // SEQ*BATCH
#define KP   416       // padded wemd (400->416) for gemm_h K
#define K2   448       // padded rank (396->448) for gemm_big K (7 tiles of 64)
#define BSTR 896       // byte stride of H and G rows (448*2)
#define NBC  2500
#define NBCP 2560

// ---- ws layout (bytes) ----
#define OFF_WBF  0u                 // u16 [16416][416]
#define OFF_UBT  13658112u          // u16 [512][416]
#define OFF_TBT  14084096u          // u16 [512][416]
#define OFF_G2   14510080u          // f32 [50][448]
#define OFF_G3   14599680u
#define OFF_G    14689280u          // u16 [2560][448]
#define OFF_H    16983040u          // u16 [16384][448]   total ~31.7 MB

__device__ __forceinline__ u16 f2bf(float f) {
  union { float f; unsigned u; } v; v.f = f;
  unsigned u = v.u;
  return (u16)((u + 0x7FFFu + ((u >> 16) & 1u)) >> 16);  // RNE
}

typedef __attribute__((address_space(3))) unsigned char lds_byte;
typedef __attribute__((address_space(1))) const unsigned char glob_byte;

__device__ __forceinline__ void gload16(const void* g, void* l) {
  __builtin_amdgcn_global_load_lds((glob_byte*)g, (lds_byte*)l, 16, 0, 0);
}

#define FENCE() asm volatile("" ::: "memory")
#define BARRIER() do { FENCE(); __builtin_amdgcn_s_barrier(); FENCE(); } while (0)
#define VMCNT4() asm volatile("s_waitcnt vmcnt(4)" ::: "memory")

// ---------- prep kernels ----------
__global__ void prep_w(const float* __restrict__ word, const float* __restrict__ first,
                       u16* __restrict__ Wbf) {
  int idx = blockIdx.x * 256 + threadIdx.x;           // over 16416*416
  if (idx >= 16416 * KP) return;
  int r = idx / KP, c = idx - r * KP;
  float v = 0.f;
  if (c < WEMD) v = (r < 32) ? first[c] : word[(size_t)(r - 32) * WEMD + c];
  Wbf[idx] = f2bf(v);
}

__global__ void prep_ut(const float* __restrict__ U, const float* __restrict__ T,
                        u16* __restrict__ Ubt, u16* __restrict__ Tbt) {
  int idx = blockIdx.x * 256 + threadIdx.x;           // over 512*416
  if (idx >= 512 * KP) return;
  int n = idx / KP, k = idx - n * KP;
  float u = 0.f, t = 0.f;
  if (n < RANK && k < WEMD) { u = U[(size_t)k * RANK + n]; t = T[(size_t)k * RANK + n]; }
  Ubt[idx] = f2bf(u); Tbt[idx] = f2bf(t);
}

__global__ void prep_g23(const float* __restrict__ tag, const float* __restrict__ V,
                         const float* __restrict__ W, float* __restrict__ g2f,
                         float* __restrict__ g3f) {
  int idx = blockIdx.x * 256 + threadIdx.x;           // over 50*448
  if (idx >= 50 * K2) return;
  int b = idx / K2, k = idx - b * K2;
  float a2 = 0.f, a3 = 0.f;
  if (k < RANK) {
    #pragma unroll
    for (int e = 0; e < 20; ++e) {
      float te = tag[b * 20 + e];
      a2 += te * V[e * RANK + k];
      a3 += te * W[e * RANK + k];
    }
  }
  g2f[idx] = a2; g3f[idx] = a3;
}

__global__ void prep_G(const float* __restrict__ g2f, const float* __restrict__ g3f,
                       u16* __restrict__ G) {
  int idx = blockIdx.x * 256 + threadIdx.x;           // over 2560*448
  if (idx >= NBCP * K2) return;
  int bc = idx / K2, k = idx - bc * K2;
  float v = 0.f;
  if (bc < NBC) {
    int b = bc / 50, c = bc - b * 50;
    v = g2f[b * K2 + k] * g3f[c * K2 + k];
  }
  G[idx] = f2bf(v);
}

// ---------- H = (word@U) * (neighbor@T), bf16 out, stride 448 ----------
__global__ __launch_bounds__(256) void gemm_h(const u16* __restrict__ Wbf,
                                              const u16* __restrict__ Ubt,
                                              const u16* __restrict__ Tbt,
                                              u16* __restrict__ H) {
  __shared__ u16 As0[128 * 32], As1[128 * 32], Bu[128 * 32], Bt[128 * 32];
  const int tid = threadIdx.x;
  const int l = tid & 63, w = tid >> 6;
  const int wm = w >> 1, wn = w & 1;
  const int tm = (blockIdx.x >> 2) * 128, tn = (blockIdx.x & 3) * 128;

  f32x4 acc0[4][4] = {}, acc1[4][4] = {};

  const int srow = tid >> 2;
  const int scolb = (tid & 3) * 16;
  const char* gA0 = (const char*)Wbf + (size_t)(tm + 32 + srow) * 832 + scolb;
  const char* gA1 = (const char*)Wbf + (size_t)(tm + srow) * 832 + scolb;
  const char* gU  = (const char*)Ubt + (size_t)(tn + srow) * 832 + scolb;
  const char* gT  = (const char*)Tbt + (size_t)(tn + srow) * 832 + scolb;
  char* lA0 = (char*)As0 + tid * 16;
  char* lA1 = (char*)As1 + tid * 16;
  char* lU  = (char*)Bu  + tid * 16;
  char* lT  = (char*)Bt  + tid * 16;

  const int fo_a = (wm * 64 + (l & 15)) * 32 + (l >> 4) * 8;
  const int fo_b = (wn * 64 + (l & 15)) * 32 + (l >> 4) * 8;

  for (int kt = 0; kt < 13; ++kt) {
    const int kb = kt * 64;
    gload16(gA0 + kb, lA0); gload16(gA0 + kb + (size_t)64 * 832, lA0 + 4096);
    gload16(gA1 + kb, lA1); gload16(gA1 + kb + (size_t)64 * 832, lA1 + 4096);
    gload16(gU  + kb, lU ); gload16(gU  + kb + (size_t)64 * 832, lU  + 4096);
    gload16(gT  + kb, lT ); gload16(gT  + kb + (size_t)64 * 832, lT  + 4096);
    __syncthreads();
    bf16x8 a0[4], a1[4], bu[4], bt[4];
    #pragma unroll
    for (int i = 0; i < 4; ++i) {
      a0[i] = *(const bf16x8*)(As0 + fo_a + i * 16 * 32);
      a1[i] = *(const bf16x8*)(As1 + fo_a + i * 16 * 32);
      bu[i] = *(const bf16x8*)(Bu  + fo_b + i * 16 * 32);
      bt[i] = *(const bf16x8*)(Bt  + fo_b + i * 16 * 32);
    }
    #pragma unroll
    for (int i = 0; i < 4; ++i)
      #pragma unroll
      for (int j = 0; j < 4; ++j) {
        acc0[i][j] = __builtin_amdgcn_mfma_f32_16x16x32_bf16(a0[i], bu[j], acc0[i][j], 0, 0, 0);
        acc1[i][j] = __builtin_amdgcn_mfma_f32_16x16x32_bf16(a1[i], bt[j], acc1[i][j], 0, 0, 0);
      }
    __syncthreads();
  }

  const int r4 = (l >> 4) * 4, cc = l & 15;
  #pragma unroll
  for (int i = 0; i < 4; ++i)
    #pragma unroll
    for (int j = 0; j < 4; ++j) {
      const int col = tn + wn * 64 + j * 16 + cc;
      if (col < K2) {
        #pragma unroll
        for (int r = 0; r < 4; ++r) {
          const int rowg = tm + wm * 64 + i * 16 + r4 + r;
          H[(size_t)rowg * K2 + col] = f2bf(acc0[i][j][r] * acc1[i][j][r]);
        }
      }
    }
}

// ---------- out[16384,2500] = H[.,448] @ G^T : 256x256 tile, 8-phase ----------
// 8 LDS half-tile slots of 16KB: slot = buf*4 + op*2 + half (op: A=0,B=1).
// Swizzle: logical byte L in slot [128 rows][128B]: physical = L ^ ((row&7)<<4).
// Stage writes linear physical, sources inverse-swizzled global (rule 21).
#define STAGE(gbase, rowbase, tt, slot)                                            \
  do {                                                                             \
    char* _d = ldsb + (slot) * 16384;                                              \
    gload16((gbase) + (size_t)((rowbase) + sr0) * BSTR + (tt) * 128 + sc0, _d + P0);\
    gload16((gbase) + (size_t)((rowbase) + sr1) * BSTR + (tt) * 128 + sc1, _d + P1);\
  } while (0)

__global__ __launch_bounds__(512, 2) void gemm_big8(const u16* __restrict__ H,
                                                    const u16* __restrict__ G,
                                                    float* __restrict__ out) {
  __shared__ u16 lds[8 * 8192];   // 128 KiB
  char* ldsb = (char*)lds;
  const int tid = threadIdx.x;
  const int lane = tid & 63, wid = tid >> 6;
  const int wm = wid >> 2, wn = wid & 3;

  int bs = (int)blockIdx.x;
  bs = (bs & 7) * 80 + (bs >> 3);                 // XCD swizzle, 640 % 8 == 0
  const int tm = (bs / 10) * 256, tn = (bs % 10) * 256;

  const char* gH = (const char*)H;
  const char* gG = (const char*)G;

  // stage addressing: physical P -> logical L (involution on bits 4-6 by row&7)
  const int P0 = tid * 16, P1 = tid * 16 + 8192;
  const int L0 = P0 ^ (((P0 >> 7) & 7) << 4);
  const int L1 = P1 ^ (((P1 >> 7) & 7) << 4);
  const int sr0 = L0 >> 7, sc0 = L0 & 127;
  const int sr1 = L1 >> 7, sc1 = L1 & 127;

  // read-side swizzled k-offsets (row&7 == lane&7 for all fragments)
  const int cs0 = ((lane >> 4) * 16) ^ ((lane & 7) << 4);
  const int cs1 = (64 + (lane >> 4) * 16) ^ ((lane & 7) << 4);
  const int arow = (lane & 15) * 128;

  f32x4 acc[8][4] = {};

  // prologue: tile0 all 4 half-tiles + tile1 {B0, A0}
  STAGE(gH, tm,       0, 0);
  STAGE(gH, tm + 128, 0, 1);
  STAGE(gG, tn,       0, 2);
  STAGE(gG, tn + 128, 0, 3);
  STAGE(gG, tn,       1, 6);
  STAGE(gH, tm,       1, 4);
  VMCNT4();
  BARRIER();

  for (int t = 0; t < 7; ++t) {
    const int cb = t & 1, nb = cb ^ 1;
    const char* bufA = ldsb + (cb * 4 + wm) * 16384;
    const char* bufB = ldsb + (cb * 4 + 2 + (wn >> 1)) * 16384;
    const int boff = (wn & 1) * 8192;
    const int t1 = (t + 1 < 7) ? t + 1 : 6;
    const int t2 = (t + 2 < 7) ? t + 2 : 6;

    bf16x8 a[4][2], b[2][2][2];

    // ---- phase 0: quadrant (rows 0-63, cols 0-31) ----
    #pragma unroll
    for (int rf = 0; rf < 4; ++rf) {
      a[rf][0] = *(const bf16x8*)(bufA + rf * 2048 + arow + cs0);
      a[rf][1] = *(const bf16x8*)(bufA + rf * 2048 + arow + cs1);
    }
    #pragma unroll
    for (int cf = 0; cf < 2; ++cf) {
      b[0][cf][0] = *(const bf16x8*)(bufB + boff + cf * 2048 + arow + cs0);
      b[0][cf][1] = *(const bf16x8*)(bufB + boff + cf * 2048 + arow + cs1);
    }
    STAGE(gH, tm + 128, t1, nb * 4 + 1);          // HT(t+1, A1)
    BARRIER();
    __builtin_amdgcn_s_setprio(1);
    #pragma unroll
    for (int rf = 0; rf < 4; ++rf)
      #pragma unroll
      for (int cf = 0; cf < 2; ++cf) {
        acc[rf][cf] = __builtin_amdgcn_mfma_f32_16x16x32_bf16(a[rf][0], b[0][cf][0], acc[rf][cf], 0, 0, 0);
        acc[rf][cf] = __builtin_amdgcn_mfma_f32_16x16x32_bf16(a[rf][1], b[0][cf][1], acc[rf][cf], 0, 0, 0);
      }
    __builtin_amdgcn_s_setprio(0);
    BARRIER();

    // ---- phase 1: quadrant (rows 0-63, cols 32-63) ----
    #pragma unroll
    for (int cf = 0; cf < 2; ++cf) {
      b[1][cf][0] = *(const bf16x8*)(bufB + boff + 4096 + cf * 2048 + arow + cs0);
      b[1][cf][1] = *(const bf16x8*)(bufB + boff + 4096 + cf * 2048 + arow + cs1);
    }
    STAGE(gG, tn + 128, t1, nb * 4 + 3);          // HT(t+1, B1)
    BARRIER();
    __builtin_amdgcn_s_setprio(1);
    #pragma unroll
    for (int rf = 0; rf < 4; ++rf)
      #pragma unroll
      for (int cf = 0; cf < 2; ++cf) {
        acc[rf][2 + cf] = __builtin_amdgcn_mfma_f32_16x16x32_bf16(a[rf][0], b[1][cf][0], acc[rf][2 + cf], 0, 0, 0);
        acc[rf][2 + cf] = __builtin_amdgcn_mfma_f32_16x16x32_bf16(a[rf][1], b[1][cf][1], acc[rf][2 + cf], 0, 0, 0);
      }
    __builtin_amdgcn_s_setprio(0);
    BARRIER();

    // ---- phase 2: quadrant (rows 64-127, cols 0-31) ----
    #pragma unroll
    for (int rf = 0; rf < 4; ++rf) {
      a[rf][0] = *(const bf16x8*)(bufA + 8192 + rf * 2048 + arow + cs0);
      a[rf][1] = *(const bf16x8*)(bufA + 8192 + rf * 2048 + arow + cs1);
    }
    STAGE(gG, tn, t2, cb * 4 + 2);                // HT(t+2, B0) -> current buf (safe after ph1)
    BARRIER();
    __builtin_amdgcn_s_setprio(1);
    #pragma unroll
    for (int rf = 0; rf < 4; ++rf)
      #pragma unroll
      for (int cf = 0; cf < 2; ++cf) {
        acc[4 + rf][cf] = __builtin_amdgcn_mfma_f32_16x16x32_bf16(a[rf][0], b[0][cf][0], acc[4 + rf][cf], 0, 0, 0);
        acc[4 + rf][cf] = __builtin_amdgcn_mfma_f32_16x16x32_bf16(a[rf][1], b[0][cf][1], acc[4 + rf][cf], 0, 0, 0);
      }
    __builtin_amdgcn_s_setprio(0);
    BARRIER();

    // ---- phase 3: quadrant (rows 64-127, cols 32-63) ----
    STAGE(gH, tm, t2, cb * 4 + 0);                // HT(t+2, A0) -> current buf (safe after ph2)
    BARRIER();
    __builtin_amdgcn_s_setprio(1);
    #pragma unroll
    for (int rf = 0; rf < 4; ++rf)
      #pragma unroll
      for (int cf = 0; cf < 2; ++cf) {
        acc[4 + rf][2 + cf] = __builtin_amdgcn_mfma_f32_16x16x32_bf16(a[rf][0], b[1][cf][0], acc[4 + rf][2 + cf], 0, 0, 0);
        acc[4 + rf][2 + cf] = __builtin_amdgcn_mfma_f32_16x16x32_bf16(a[rf][1], b[1][cf][1], acc[4 + rf][2 + cf], 0, 0, 0);
      }
    __builtin_amdgcn_s_setprio(0);
    VMCNT4();                                     // counted wait: tile t+1 fully resident
    BARRIER();
  }

  const int r4 = (lane >> 4) * 4, cc = lane & 15;
  const int rbase = tm + wm * 128 + r4;
  const int cbase = tn + wn * 64 + cc;
  #pragma unroll
  for (int rf = 0; rf < 8; ++rf)
    #pragma unroll
    for (int cf = 0; cf < 4; ++cf) {
      const int col = cbase + cf * 16;
      if (col < NBC) {
        #pragma unroll
        for (int rr = 0; rr < 4; ++rr)
          out[(size_t)(rbase + rf * 16 + rr) * NBC + col] = acc[rf][cf][rr];
      }
    }
}

extern "C" void kernel_launch(void* const* d_in, const int* in_sizes, int n_in,
                              void* d_out, int out_size, void* d_ws, size_t ws_size,
                              hipStream_t stream) {
  const float* word  = (const float*)d_in[0];
  const float* tag   = (const float*)d_in[1];
  const float* Tm    = (const float*)d_in[2];
  const float* Um    = (const float*)d_in[3];
  const float* Vm    = (const float*)d_in[4];
  const float* Wm    = (const float*)d_in[5];
  const float* first = (const float*)d_in[6];
  float* out = (float*)d_out;
  char* ws = (char*)d_ws;

  u16*   Wbf = (u16*)(ws + OFF_WBF);
  u16*   Ubt = (u16*)(ws + OFF_UBT);
  u16*   Tbt = (u16*)(ws + OFF_TBT);
  float* g2f = (float*)(ws + OFF_G2);
  float* g3f = (float*)(ws + OFF_G3);
  u16*   G   = (u16*)(ws + OFF_G);
  u16*   H   = (u16*)(ws + OFF_H);

  hipLaunchKernelGGL(prep_w,   dim3((16416 * KP + 255) / 256), dim3(256), 0, stream, word, first, Wbf);
  hipLaunchKernelGGL(prep_ut,  dim3((512 * KP + 255) / 256),   dim3(256), 0, stream, Um, Tm, Ubt, Tbt);
  hipLaunchKernelGGL(prep_g23, dim3((50 * K2 + 255) / 256),    dim3(256), 0, stream, tag, Vm, Wm, g2f, g3f);
  hipLaunchKernelGGL(prep_G,   dim3((NBCP * K2 + 255) / 256),  dim3(256), 0, stream, g2f, g3f, G);
  hipLaunchKernelGGL(gemm_h,   dim3(128 * 4), dim3(256), 0, stream, Wbf, Ubt, Tbt, H);
  hipLaunchKernelGGL(gemm_big8, dim3(640),    dim3(512), 0, stream, H, G, out);
}